// Round 16
// baseline (216.709 us; speedup 1.0000x reference)
//
#include <hip/hip_runtime.h>
#include <hip/hip_bf16.h>
#include <math.h>

#define BB 4
#define CC 64
#define HH 128
#define WW 128
#define DD 128
#define NN 64
#define HF 128
#define WF 65
#define LL 8320
#define TSEG 64
#define NSEG 130
#define PI2f 6.283185307179586f

__device__ __forceinline__ int brev7(int x) { return (int)(__brev((unsigned)x) >> 25); }

// ---------------- K0: weight transposes (WcatT[k][o] 128x256, WoT[d][e] 128x128) ----
__global__ void k0_transpose(const float* __restrict__ Wx, const float* __restrict__ Wb,
                             const float* __restrict__ Wc, const float* __restrict__ Wout,
                             float* __restrict__ WcatT, float* __restrict__ WoT) {
  int idx = blockIdx.x * 256 + threadIdx.x;
  if (idx < 128 * 256) {
    int k = idx >> 8, o = idx & 255;
    float v;
    if (o < 128)      v = Wx[o * 128 + k];
    else if (o < 192) v = Wb[(o - 128) * 128 + k];
    else              v = Wc[(o - 192) * 128 + k];
    WcatT[k * 256 + o] = v;
  }
  if (idx < 128 * 128) {
    int d = idx >> 7, e = idx & 127;
    WoT[d * 128 + e] = Wout[e * 128 + d];
  }
}

// ---------------- K1: rfft along W via paired 128-pt complex FFT (16 pairs/block) --
__global__ __launch_bounds__(256) void k1_rfft(const float* __restrict__ x,
                                               float* __restrict__ T1) {
  __shared__ float2 data[128 * 17];
  __shared__ float2 tw[64];
  int tid = threadIdx.x;
  if (tid < 64) {
    float sv, cv;
    sincosf(PI2f * (float)tid * (1.f / 128.f), &sv, &cv);
    tw[tid] = make_float2(cv, sv);
  }
  int r0 = blockIdx.x * 32;            // 32 rows = 16 pairs
  const float* xp = x + (size_t)r0 * 128;
#pragma unroll
  for (int i = 0; i < 8; i++) {
    int e = i * 256 + tid;             // 2048: p = e>>7, j = e&127
    int p = e >> 7, j = e & 127;
    float v1 = xp[(2 * p) * 128 + j];
    float v2 = xp[(2 * p + 1) * 128 + j];
    data[brev7(j) * 17 + p] = make_float2(v1, v2);
  }
  __syncthreads();
  for (int s = 1; s <= 7; s++) {
    int half = 1 << (s - 1);
    int tsh = 7 - s;
#pragma unroll
    for (int i = 0; i < 4; i++) {
      int idx = i * 256 + tid;         // 1024 butterflies: t = idx>>4, c = idx&15
      int t = idx >> 4, c = idx & 15;
      int j = t & (half - 1);
      int pos = ((t >> (s - 1)) << s) + j;
      float2 a = data[pos * 17 + c];
      float2 b = data[(pos + half) * 17 + c];
      float2 w = tw[j << tsh];
      float2 m = make_float2(b.x * w.x + b.y * w.y, b.y * w.x - b.x * w.y);  // e^{-i}
      data[pos * 17 + c] = make_float2(a.x + m.x, a.y + m.y);
      data[(pos + half) * 17 + c] = make_float2(a.x - m.x, a.y - m.y);
    }
    __syncthreads();
  }
  const float inv = 1.f / 128.f;
  float2* o = (float2*)T1 + (size_t)r0 * 65;
#pragma unroll
  for (int i = 0; i < 5; i++) {
    int e = i * 256 + tid;             // 16 pairs x 65 bins = 1040
    if (e < 1040) {
      int p = e / 65, k = e - p * 65;
      float2 Z = data[k * 17 + p];
      float2 Zc = data[((128 - k) & 127) * 17 + p];
      float2 X1 = make_float2((Z.x + Zc.x) * 0.5f * inv, (Z.y - Zc.y) * 0.5f * inv);
      float2 X2 = make_float2((Z.y + Zc.y) * 0.5f * inv, (Zc.x - Z.x) * 0.5f * inv);
      o[(2 * p) * 65 + k] = X1;
      o[(2 * p + 1) * 65 + k] = X2;
    }
  }
}

// ---------------- K2a: radix-2 FFT (forward) along H, 17 wf-cols per block ---------
// block = (bc, chunk of 4). chunk c covers wf [16c, 16c+16]; overlap cols benign.
__global__ __launch_bounds__(256) void k2a_fft(const float* __restrict__ T1,
                                               float* __restrict__ uT) {
  __shared__ float2 data[128 * 17];
  __shared__ float2 tw[64];
  int tid = threadIdx.x;
  if (tid < 64) {
    float sv, cv;
    sincosf(PI2f * (float)tid * (1.f / 128.f), &sv, &cv);
    tw[tid] = make_float2(cv, sv);
  }
  int chunk = blockIdx.x & 3;
  int bc = blockIdx.x >> 2;
  int wf0 = chunk * 16;
  const float2* Tp = (const float2*)T1 + (size_t)bc * 8320;  // [j][wf], 65-wide
#pragma unroll
  for (int i = 0; i < 9; i++) {
    int e = i * 256 + tid;  // e = j*17 + c
    if (e < 2176) {
      int j = e / 17;
      int c = e - j * 17;
      data[brev7(j) * 17 + c] = Tp[j * 65 + wf0 + c];
    }
  }
  __syncthreads();
  for (int s = 1; s <= 7; s++) {
    int half = 1 << (s - 1);
    int tsh = 7 - s;
#pragma unroll
    for (int i = 0; i < 5; i++) {
      int idx = i * 256 + tid;
      if (idx < 1088) {
        int t = idx / 17;
        int c = idx - t * 17;
        int j = t & (half - 1);
        int pos = ((t >> (s - 1)) << s) + j;
        float2 a = data[pos * 17 + c];
        float2 b = data[(pos + half) * 17 + c];
        float2 w = tw[j << tsh];
        float2 m = make_float2(b.x * w.x + b.y * w.y, b.y * w.x - b.x * w.y);  // b*e^{-i}
        data[pos * 17 + c] = make_float2(a.x + m.x, a.y + m.y);
        data[(pos + half) * 17 + c] = make_float2(a.x - m.x, a.y - m.y);
      }
    }
    __syncthreads();
  }
  int b = bc >> 6, ch = bc & 63;
  float* pr = uT + (size_t)(b * 128 + ch) * 8320;
  float* pi = uT + (size_t)(b * 128 + 64 + ch) * 8320;
#pragma unroll
  for (int i = 0; i < 9; i++) {
    int e = i * 256 + tid;
    if (e < 2176) {
      int hf = e / 17;
      int c = e - hf * 17;
      float2 v = data[hf * 17 + c];
      pr[hf * 65 + wf0 + c] = v.x;
      pi[hf * 65 + wf0 + c] = v.y;
    }
  }
}

// ---------------- K3: LN + projections; 32-token tile, 256 thr, grid 1040 ----------
__global__ __launch_bounds__(256) void k3_ln_proj(
    const float* __restrict__ uT, const float* __restrict__ WcatT,
    const float* __restrict__ nw, const float* __restrict__ nb,
    const float* __restrict__ wdt, const float* __restrict__ dtbias,
    float* __restrict__ xs, float* __restrict__ Bs, float* __restrict__ Cs,
    float* __restrict__ dtb) {
  __shared__ float su[128 * 36];       // [k][t], stride 36
  __shared__ float snw[128], snb[128], swdt[128];
  int tid = threadIdx.x;               // 0..255
  int b = blockIdx.x / 260, tile = blockIdx.x % 260;
  int l0 = tile * 32;
  if (tid < 128) { snw[tid] = nw[tid]; snb[tid] = nb[tid]; swdt[tid] = wdt[tid]; }
  const float* up = uT + (size_t)b * 128 * 8320 + l0;
#pragma unroll
  for (int i = 0; i < 4; i++) {
    int e = i * 256 + tid;             // 1024 f4: d = e>>3, q = e&7
    int d = e >> 3, q = e & 7;
    float4 v = *(const float4*)(up + (size_t)d * 8320 + q * 4);
    *(float4*)&su[d * 36 + q * 4] = v;
  }
  __syncthreads();
  // LayerNorm: 8 threads per token (j=0..7), 16 channels each, in-place in su
  int t = tid >> 3, j = tid & 7;       // t 0..31
  float vals[16];
  float s = 0.f, s2 = 0.f;
#pragma unroll
  for (int i = 0; i < 16; i++) {
    float v = su[(8 * i + j) * 36 + t];
    vals[i] = v; s += v; s2 += v * v;
  }
  s += __shfl_xor(s, 1, 64);  s += __shfl_xor(s, 2, 64);  s += __shfl_xor(s, 4, 64);
  s2 += __shfl_xor(s2, 1, 64); s2 += __shfl_xor(s2, 2, 64); s2 += __shfl_xor(s2, 4, 64);
  float mu = s * (1.f / 128.f);
  float var = s2 * (1.f / 128.f) - mu * mu;
  float rs = rsqrtf(var + 1e-5f);
  float raw = 0.f;
#pragma unroll
  for (int i = 0; i < 16; i++) {
    int k = 8 * i + j;
    float v = ((vals[i] - mu) * rs * snw[k] + snb[k]) * (1.f / 128.f);
    su[k * 36 + t] = v;
    raw = fmaf(v, swdt[k], raw);
  }
  raw += __shfl_xor(raw, 1, 64); raw += __shfl_xor(raw, 2, 64); raw += __shfl_xor(raw, 4, 64);
  if (j == 0) {
    float z = raw + dtbias[0];
    float sp = fmaxf(z, 0.f) + log1pf(expf(-fabsf(z)));
    dtb[b * LL + l0 + t] = sp;
  }
  __syncthreads();
  // GEMM: wave = 8-token group (4 waves), lane = f4 of 256 outputs
  int wv = tid >> 6;                   // 0..3
  int lane = tid & 63;
  int t0 = wv * 8;
  float acc[8][4];
#pragma unroll
  for (int i = 0; i < 8; i++)
#pragma unroll
    for (int r = 0; r < 4; r++) acc[i][r] = 0.f;
  const float4* W4 = (const float4*)WcatT;
  for (int k = 0; k < 128; k++) {
    float4 w = W4[k * 64 + lane];
    const float4* sr4 = (const float4*)&su[k * 36 + t0];
    float4 u0 = sr4[0], u1 = sr4[1];
    float uk[8] = {u0.x, u0.y, u0.z, u0.w, u1.x, u1.y, u1.z, u1.w};
#pragma unroll
    for (int i = 0; i < 8; i++) {
      acc[i][0] = fmaf(w.x, uk[i], acc[i][0]);
      acc[i][1] = fmaf(w.y, uk[i], acc[i][1]);
      acc[i][2] = fmaf(w.z, uk[i], acc[i][2]);
      acc[i][3] = fmaf(w.w, uk[i], acc[i][3]);
    }
  }
  size_t tok0 = (size_t)b * LL + l0 + t0;
  float* basep;
  size_t stride;
  if (lane < 32)      { basep = xs + tok0 * 128 + lane * 4;        stride = 128; }
  else if (lane < 48) { basep = Bs + tok0 * 64 + (lane - 32) * 4;  stride = 64; }
  else                { basep = Cs + tok0 * 64 + (lane - 48) * 4;  stride = 64; }
#pragma unroll
  for (int i = 0; i < 8; i++)
    *(float4*)(basep + (size_t)i * stride) =
        make_float4(acc[i][0], acc[i][1], acc[i][2], acc[i][3]);
}

// ---------------- K5: half-D split (grid 1040), X from global, B/C in LDS ----------
__global__ __launch_bounds__(256) void k5_seg(
    const float* __restrict__ xs, const float* __restrict__ Bs, const float* __restrict__ Cs,
    const float* __restrict__ dtb, const float* __restrict__ Alog,
    const float* __restrict__ Dskip,
    float* __restrict__ ybuf, float* __restrict__ Sseg, float* __restrict__ ssegb,
    float* __restrict__ cumg) {
  __shared__ __align__(16) float sB[64 * 68];
  __shared__ __align__(16) float sCM[64 * 68];
  __shared__ float sdt[64], slc[64], sws[64];
  int tid = threadIdx.x;
  int half = blockIdx.x & 1;
  int bs = blockIdx.x >> 1;
  int b = bs / NSEG, seg = bs % NSEG;
  int tokbase = b * LL + seg * TSEG;
  const float4* xg = (const float4*)(xs + (size_t)tokbase * 128);  // [t][32 f4]
  const float4* bg = (const float4*)(Bs + (size_t)tokbase * 64);
  const float4* cg = (const float4*)(Cs + (size_t)tokbase * 64);
#pragma unroll
  for (int i = 0; i < 4; i++) {
    int e = i * 256 + tid;
    int t = e >> 4, n4 = e & 15;
    *(float4*)&sB[t * 68 + n4 * 4] = bg[e];
    *(float4*)&sCM[t * 68 + n4 * 4] = cg[e];
  }
  if (tid < 64) sdt[tid] = dtb[tokbase + tid];
  __syncthreads();
  if (tid < 64) {
    float a = expf(Alog[0]);
    float v = -a * sdt[tid];
#pragma unroll
    for (int off = 1; off < 64; off <<= 1) {
      float o = __shfl_up(v, off, 64);
      if (tid >= off) v += o;
    }
    slc[tid] = v;
    float l63 = __shfl(v, 63, 64);
    sws[tid] = expf(l63 - v) * sdt[tid];
    if (half == 0) {
      cumg[tokbase + tid] = expf(v);
      if (tid == 63) ssegb[seg * BB + b] = expf(v);
    }
  }
  __syncthreads();
  // ---- G = C . B^T (redundant per half; small)
  int t0 = (tid >> 4) * 4, s0 = (tid & 15) * 4;
  float g[4][4];
#pragma unroll
  for (int i = 0; i < 4; i++)
#pragma unroll
    for (int j = 0; j < 4; j++) g[i][j] = 0.f;
  for (int n4 = 0; n4 < 16; n4++) {
    float4 cr[4], br[4];
#pragma unroll
    for (int i = 0; i < 4; i++) cr[i] = *(const float4*)&sCM[(t0 + i) * 68 + n4 * 4];
#pragma unroll
    for (int j = 0; j < 4; j++) br[j] = *(const float4*)&sB[(s0 + j) * 68 + n4 * 4];
#pragma unroll
    for (int i = 0; i < 4; i++)
#pragma unroll
      for (int j = 0; j < 4; j++) {
        g[i][j] = fmaf(cr[i].x, br[j].x, g[i][j]);
        g[i][j] = fmaf(cr[i].y, br[j].y, g[i][j]);
        g[i][j] = fmaf(cr[i].z, br[j].z, g[i][j]);
        g[i][j] = fmaf(cr[i].w, br[j].w, g[i][j]);
      }
  }
  __syncthreads();
  // ---- M (masked, scaled) into sCM
#pragma unroll
  for (int i = 0; i < 4; i++) {
    int t = t0 + i;
    float4 m;
    float lt = slc[t];
    m.x = (s0 + 0 <= t) ? expf(lt - slc[s0 + 0]) * sdt[s0 + 0] * g[i][0] : 0.f;
    m.y = (s0 + 1 <= t) ? expf(lt - slc[s0 + 1]) * sdt[s0 + 1] * g[i][1] : 0.f;
    m.z = (s0 + 2 <= t) ? expf(lt - slc[s0 + 2]) * sdt[s0 + 2] * g[i][2] : 0.f;
    m.w = (s0 + 3 <= t) ? expf(lt - slc[s0 + 3]) * sdt[s0 + 3] * g[i][3] : 0.f;
    *(float4*)&sCM[t * 68 + s0] = m;
  }
  __syncthreads();
  // ---- Y(half) = M . X + Dskip*X : thread = 4 tokens x 4 d ; X from global (L2)
  {
    int q = half * 16 + (tid & 15);    // f4 index into token row
    int d0 = (tid & 15) * 4;
    float acc[4][4];
#pragma unroll
    for (int i = 0; i < 4; i++)
#pragma unroll
      for (int j = 0; j < 4; j++) acc[i][j] = 0.f;
    for (int s = 0; s < 64; s++) {
      float4 xv = xg[s * 32 + q];
#pragma unroll
      for (int i = 0; i < 4; i++) {
        float m = sCM[(t0 + i) * 68 + s];
        acc[i][0] = fmaf(m, xv.x, acc[i][0]);
        acc[i][1] = fmaf(m, xv.y, acc[i][1]);
        acc[i][2] = fmaf(m, xv.z, acc[i][2]);
        acc[i][3] = fmaf(m, xv.w, acc[i][3]);
      }
    }
    float4 dk = *(const float4*)&Dskip[half * 64 + d0];
#pragma unroll
    for (int i = 0; i < 4; i++) {
      int t = t0 + i;
      float4 xv = xg[t * 32 + q];
      float4 y;
      y.x = fmaf(dk.x, xv.x, acc[i][0]);
      y.y = fmaf(dk.y, xv.y, acc[i][1]);
      y.z = fmaf(dk.z, xv.z, acc[i][2]);
      y.w = fmaf(dk.w, xv.w, acc[i][3]);
      *(float4*)(ybuf + (size_t)(tokbase + t) * 128 + half * 64 + d0) = y;
    }
  }
  // ---- S(half)[d,n] : thread = 4 d x 4 n ; X from global (L2)
  {
    int q2 = half * 16 + (tid >> 4);   // f4 index
    int dd0 = (tid >> 4) * 4, n0 = (tid & 15) * 4;
    float sacc[4][4];
#pragma unroll
    for (int k = 0; k < 4; k++)
#pragma unroll
      for (int j = 0; j < 4; j++) sacc[k][j] = 0.f;
    for (int s = 0; s < 64; s++) {
      float w = sws[s];
      float4 b4 = *(const float4*)&sB[s * 68 + n0];
      b4.x *= w; b4.y *= w; b4.z *= w; b4.w *= w;
      float4 xv = xg[s * 32 + q2];
      float xk[4] = {xv.x, xv.y, xv.z, xv.w};
#pragma unroll
      for (int k = 0; k < 4; k++) {
        sacc[k][0] = fmaf(xk[k], b4.x, sacc[k][0]);
        sacc[k][1] = fmaf(xk[k], b4.y, sacc[k][1]);
        sacc[k][2] = fmaf(xk[k], b4.z, sacc[k][2]);
        sacc[k][3] = fmaf(xk[k], b4.w, sacc[k][3]);
      }
    }
    float* Sp = Sseg + (size_t)seg * 32768 + (size_t)b * 8192;
#pragma unroll
    for (int k = 0; k < 4; k++)
      *(float4*)&Sp[(half * 64 + dd0 + k) * 64 + n0] =
          make_float4(sacc[k][0], sacc[k][1], sacc[k][2], sacc[k][3]);
  }
}

// ---------------- K5b: segment-boundary state recurrence + h_last ------------------
__global__ void k5b_states(const float* __restrict__ h_prev, const float* __restrict__ Sseg,
                           const float* __restrict__ ssegb, float* __restrict__ Hp,
                           float* __restrict__ h_last) {
  int gid = blockIdx.x * 256 + threadIdx.x;
  int b = gid >> 13;
  float h = h_prev[gid];
  for (int p = 0; p < NSEG; p++) {
    Hp[(size_t)p * 32768 + gid] = h;
    h = fmaf(ssegb[p * 4 + b], h, Sseg[(size_t)p * 32768 + gid]);
  }
  h_last[gid] = h;
}

// ---------------- K5c: inter-segment correction, 512 thr ---------------------------
__global__ __launch_bounds__(512) void k5c_correct(
    const float* __restrict__ Cs, const float* __restrict__ Hp,
    const float* __restrict__ cumg, float* __restrict__ ybuf) {
  __shared__ __align__(16) float Ct[64 * 64];
  __shared__ __align__(16) float Ht[64 * 132];
  __shared__ float cg[64];
  int tid = threadIdx.x;               // 0..511
  int b = blockIdx.x / NSEG, seg = blockIdx.x % NSEG;
  int tokbase = b * LL + seg * 64;
  const float* Csrc = Cs + (size_t)tokbase * 64;
#pragma unroll
  for (int i = 0; i < 8; i++) {
    int e = tid + i * 512;
    Ct[(e & 63) * 64 + (e >> 6)] = Csrc[e];
  }
  const float* Hsrc = Hp + (size_t)seg * 32768 + (size_t)b * 8192;
#pragma unroll
  for (int i = 0; i < 16; i++) {
    int e = tid + i * 512;
    Ht[(e & 63) * 132 + (e >> 6)] = Hsrc[e];
  }
  if (tid < 64) cg[tid] = cumg[tokbase + tid];
  __syncthreads();
  int og = tid & 15, tg = tid >> 4;    // tg 0..31
  int d0 = og * 8, t0 = tg * 2;
  float acc[2][8];
#pragma unroll
  for (int i = 0; i < 2; i++)
#pragma unroll
    for (int jj = 0; jj < 8; jj++) acc[i][jj] = 0.f;
  for (int n = 0; n < 64; n++) {
    float2 c2 = *(const float2*)&Ct[n * 64 + t0];
    float4 h0 = *(const float4*)&Ht[n * 132 + d0];
    float4 h1 = *(const float4*)&Ht[n * 132 + d0 + 4];
    float cv[2] = {c2.x, c2.y};
    float hv[8] = {h0.x, h0.y, h0.z, h0.w, h1.x, h1.y, h1.z, h1.w};
#pragma unroll
    for (int i = 0; i < 2; i++)
#pragma unroll
      for (int jj = 0; jj < 8; jj++) acc[i][jj] = fmaf(cv[i], hv[jj], acc[i][jj]);
  }
#pragma unroll
  for (int i = 0; i < 2; i++) {
    float sc = cg[t0 + i];
    float* yp = ybuf + (size_t)(tokbase + t0 + i) * 128 + d0;
    float4 y0 = *(float4*)yp;
    float4 y1 = *(float4*)(yp + 4);
    y0.x = fmaf(sc, acc[i][0], y0.x); y0.y = fmaf(sc, acc[i][1], y0.y);
    y0.z = fmaf(sc, acc[i][2], y0.z); y0.w = fmaf(sc, acc[i][3], y0.w);
    y1.x = fmaf(sc, acc[i][4], y1.x); y1.y = fmaf(sc, acc[i][5], y1.y);
    y1.z = fmaf(sc, acc[i][6], y1.z); y1.w = fmaf(sc, acc[i][7], y1.w);
    *(float4*)yp = y0; *(float4*)(yp + 4) = y1;
  }
}

// ---------------- K6: output projection; 32-token tile, 256 thr, grid 1040 ---------
__global__ __launch_bounds__(256) void k6_outproj(
    const float* __restrict__ ybuf, const float* __restrict__ WoT,
    float* __restrict__ T2) {
  __shared__ float sy[128 * 36];   // [k][t] stride 36
  int tid = threadIdx.x;           // 0..255
  int b = blockIdx.x / 260, tile = blockIdx.x % 260;
  int l0 = tile * 32;
  const float* yg = ybuf + ((size_t)b * LL + l0) * 128;
#pragma unroll
  for (int i = 0; i < 4; i++) {
    int e = i * 256 + tid;           // 1024 f4: t = e>>5, q = e&31
    int t = e >> 5, q = e & 31;
    float4 v = *(const float4*)(yg + t * 128 + q * 4);
    sy[(q * 4 + 0) * 36 + t] = v.x; sy[(q * 4 + 1) * 36 + t] = v.y;
    sy[(q * 4 + 2) * 36 + t] = v.z; sy[(q * 4 + 3) * 36 + t] = v.w;
  }
  __syncthreads();
  // wave = 8-token group (4 waves); lane: th = lane>>5 (4-token half), o4 = lane&31
  int wv = tid >> 6;               // 0..3
  int lane = tid & 63;
  int o4 = lane & 31, th = lane >> 5;
  int tt0 = wv * 8 + th * 4;
  float acc[4][4];
#pragma unroll
  for (int i = 0; i < 4; i++)
#pragma unroll
    for (int r = 0; r < 4; r++) acc[i][r] = 0.f;
  const float4* W4 = (const float4*)WoT;
  for (int k = 0; k < 128; k++) {
    float4 w = W4[k * 32 + o4];
    const float4* sr4 = (const float4*)&sy[k * 36 + tt0];
    float4 u0 = sr4[0];
    float yk[4] = {u0.x, u0.y, u0.z, u0.w};
#pragma unroll
    for (int i = 0; i < 4; i++) {
      acc[i][0] = fmaf(w.x, yk[i], acc[i][0]);
      acc[i][1] = fmaf(w.y, yk[i], acc[i][1]);
      acc[i][2] = fmaf(w.z, yk[i], acc[i][2]);
      acc[i][3] = fmaf(w.w, yk[i], acc[i][3]);
    }
  }
#pragma unroll
  for (int i = 0; i < 4; i++) {
    int l = l0 + tt0 + i;
    *(float4*)(T2 + ((size_t)b * LL + l) * 128 + o4 * 4) =
        make_float4(acc[i][0] * 128.f, acc[i][1] * 128.f,
                    acc[i][2] * 128.f, acc[i][3] * 128.f);
  }
}

// ---------------- K7t: transpose T2[b][l][e] -> T2T[b][c][l] float2 ----------------
__global__ __launch_bounds__(256) void k7t_transpose(const float* __restrict__ T2,
                                                     float* __restrict__ T2T) {
  __shared__ __align__(16) float tile[32][132];
  int tid = threadIdx.x;
  int b = blockIdx.x / 260, lt = blockIdx.x % 260;
  int l0 = lt * 32;
#pragma unroll
  for (int i = 0; i < 4; i++) {
    int e = i * 256 + tid;  // 1024: 32 l x 32 f4
    int l = e >> 5, f4 = e & 31;
    float4 v = *(const float4*)(T2 + ((size_t)(b * LL + l0 + l)) * 128 + f4 * 4);
    *(float4*)&tile[l][f4 * 4] = v;
  }
  __syncthreads();
  int l = tid & 31, c2 = tid >> 5;  // c2 0..7
  float2* out = (float2*)T2T;
#pragma unroll
  for (int k = 0; k < 8; k++) {
    int c = c2 * 8 + k;
    float2 z = make_float2(tile[l][c], tile[l][64 + c]);
    out[((size_t)(b * 64 + c)) * 8320 + l0 + l] = z;
  }
}

// ---------------- K7a: radix-2 FFT (inverse) along H, 17 wf-cols per block ---------
__global__ __launch_bounds__(256) void k7a_fft(const float* __restrict__ T2T,
                                               float* __restrict__ TY) {
  __shared__ float2 data[128 * 17];
  __shared__ float2 tw[64];
  int tid = threadIdx.x;
  if (tid < 64) {
    float sv, cv;
    sincosf(PI2f * (float)tid * (1.f / 128.f), &sv, &cv);
    tw[tid] = make_float2(cv, sv);
  }
  int chunk = blockIdx.x & 3;
  int bc = blockIdx.x >> 2;
  int wf0 = chunk * 16;
  const float2* Zp = (const float2*)T2T + (size_t)bc * 8320;  // [j][wf], 65-wide
#pragma unroll
  for (int i = 0; i < 9; i++) {
    int e = i * 256 + tid;  // e = j*17 + c
    if (e < 2176) {
      int j = e / 17;
      int c = e - j * 17;
      data[brev7(j) * 17 + c] = Zp[j * 65 + wf0 + c];
    }
  }
  __syncthreads();
  for (int s = 1; s <= 7; s++) {
    int half = 1 << (s - 1);
    int tsh = 7 - s;
#pragma unroll
    for (int i = 0; i < 5; i++) {
      int idx = i * 256 + tid;
      if (idx < 1088) {
        int t = idx / 17;
        int c = idx - t * 17;
        int j = t & (half - 1);
        int pos = ((t >> (s - 1)) << s) + j;
        float2 a = data[pos * 17 + c];
        float2 b = data[(pos + half) * 17 + c];
        float2 w = tw[j << tsh];
        float2 m = make_float2(b.x * w.x - b.y * w.y, b.y * w.x + b.x * w.y);  // b*e^{+i}
        data[pos * 17 + c] = make_float2(a.x + m.x, a.y + m.y);
        data[(pos + half) * 17 + c] = make_float2(a.x - m.x, a.y - m.y);
      }
    }
    __syncthreads();
  }
  float2* po = (float2*)TY + (size_t)bc * 8320;
#pragma unroll
  for (int i = 0; i < 9; i++) {
    int e = i * 256 + tid;
    if (e < 2176) {
      int h = e / 17;
      int c = e - h * 17;
      po[h * 65 + wf0 + c] = data[h * 17 + c];
    }
  }
}

// ---------------- K8: irfft along W via paired Hermitian inverse FFT ---------------
__global__ __launch_bounds__(256) void k8_irfft(const float* __restrict__ TY,
                                                float* __restrict__ out) {
  __shared__ float2 zsh[32 * 66];
  __shared__ float2 data[128 * 17];
  __shared__ float2 tw[64];
  int tid = threadIdx.x;
  if (tid < 64) {
    float sv, cv;
    sincosf(PI2f * (float)tid * (1.f / 128.f), &sv, &cv);
    tw[tid] = make_float2(cv, sv);
  }
  int r0 = blockIdx.x * 32;            // 32 rows = 16 pairs
  const float2* Zp = (const float2*)TY + (size_t)r0 * 65;
#pragma unroll
  for (int i = 0; i < 9; i++) {
    int e = i * 256 + tid;             // 32*65 = 2080
    if (e < 2080) {
      int r = e / 65, wf = e - r * 65;
      zsh[r * 66 + wf] = Zp[r * 65 + wf];
    }
  }
  __syncthreads();
#pragma unroll
  for (int i = 0; i < 8; i++) {
    int e = i * 256 + tid;             // 2048: p = e>>7, j = e&127
    int p = e >> 7, j = e & 127;
    int jj = (j <= 64) ? j : 128 - j;
    float2 a1 = zsh[(2 * p) * 66 + jj];
    float2 a2 = zsh[(2 * p + 1) * 66 + jj];
    if (jj == 0 || jj == 64) { a1.y = 0.f; a2.y = 0.f; }
    float2 V = (j <= 64) ? make_float2(a1.x - a2.y, a1.y + a2.x)
                         : make_float2(a1.x + a2.y, a2.x - a1.y);
    data[brev7(j) * 17 + p] = V;
  }
  __syncthreads();
  for (int s = 1; s <= 7; s++) {
    int half = 1 << (s - 1);
    int tsh = 7 - s;
#pragma unroll
    for (int i = 0; i < 4; i++) {
      int idx = i * 256 + tid;         // 1024
      int t = idx >> 4, c = idx & 15;
      int j = t & (half - 1);
      int pos = ((t >> (s - 1)) << s) + j;
      float2 a = data[pos * 17 + c];
      float2 b = data[(pos + half) * 17 + c];
      float2 w = tw[j << tsh];
      float2 m = make_float2(b.x * w.x - b.y * w.y, b.y * w.x + b.x * w.y);  // e^{+i}
      data[pos * 17 + c] = make_float2(a.x + m.x, a.y + m.y);
      data[(pos + half) * 17 + c] = make_float2(a.x - m.x, a.y - m.y);
    }
    __syncthreads();
  }
  const float inv = 1.f / 128.f;
  float* op = out + (size_t)r0 * 128;
#pragma unroll
  for (int i = 0; i < 8; i++) {
    int e = i * 256 + tid;             // 2048: p = e>>7, w = e&127
    int p = e >> 7, w = e & 127;
    float2 X = data[w * 17 + p];
    op[(2 * p) * 128 + w] = X.x * inv;
    op[(2 * p + 1) * 128 + w] = X.y * inv;
  }
}

extern "C" void kernel_launch(void* const* d_in, const int* in_sizes, int n_in,
                              void* d_out, int out_size, void* d_ws, size_t ws_size,
                              hipStream_t stream) {
  const float* x      = (const float*)d_in[0];
  const float* h_prev = (const float*)d_in[1];
  const float* nw     = (const float*)d_in[2];
  const float* nb     = (const float*)d_in[3];
  const float* Wx     = (const float*)d_in[4];
  const float* Wb     = (const float*)d_in[5];
  const float* Wc     = (const float*)d_in[6];
  const float* wdt    = (const float*)d_in[7];
  const float* dtbias = (const float*)d_in[8];
  const float* Alog   = (const float*)d_in[9];
  const float* Dskip  = (const float*)d_in[10];
  const float* Wout   = (const float*)d_in[11];
  float* out = (float*)d_out;

  float* ws = (float*)d_ws;
  const size_t SZ_BIG = 4259840;  // B*L*D
  const size_t SZ_BN  = 2129920;  // B*L*N
  float* RA = ws;                 // T1 -> xs -> Hp -> TY
  float* RB = RA + SZ_BIG;        // uT -> ybuf
  float* RC = RB + SZ_BIG;        // Sseg -> T2
  float* RD = RC + SZ_BIG;        // Bs -> T2T (spans RD+RE)
  float* RE = RD + SZ_BN;         // Cs
  float* dtb   = RE + SZ_BN;      // 33280
  float* cumg  = dtb + 33280;     // 33280
  float* ssegb = cumg + 33280;    // 520
  float* WcatT = ssegb + 520;     // 32768
  float* WoT   = WcatT + 32768;   // 16384

  hipLaunchKernelGGL(k0_transpose, dim3(128), dim3(256), 0, stream, Wx, Wb, Wc, Wout, WcatT, WoT);
  hipLaunchKernelGGL(k1_rfft, dim3(1024), dim3(256), 0, stream, x, RA /*T1*/);
  hipLaunchKernelGGL(k2a_fft, dim3(1024), dim3(256), 0, stream, RA /*T1*/, RB /*uT*/);
  hipLaunchKernelGGL(k3_ln_proj, dim3(1040), dim3(256), 0, stream,
                     RB /*uT*/, WcatT, nw, nb, wdt, dtbias, RA /*xs*/, RD /*Bs*/, RE /*Cs*/, dtb);
  hipLaunchKernelGGL(k5_seg, dim3(1040), dim3(256), 0, stream,
                     RA /*xs*/, RD /*Bs*/, RE /*Cs*/, dtb, Alog, Dskip,
                     RB /*ybuf*/, RC /*Sseg*/, ssegb, cumg);
  hipLaunchKernelGGL(k5b_states, dim3(128), dim3(256), 0, stream,
                     h_prev, RC /*Sseg*/, ssegb, RA /*Hp*/, out + 4194304);
  hipLaunchKernelGGL(k5c_correct, dim3(520), dim3(512), 0, stream,
                     RE /*Cs*/, RA /*Hp*/, cumg, RB /*ybuf*/);
  hipLaunchKernelGGL(k6_outproj, dim3(1040), dim3(256), 0, stream, RB /*ybuf*/, WoT, RC /*T2*/);
  hipLaunchKernelGGL(k7t_transpose, dim3(1040), dim3(256), 0, stream, RC /*T2*/, RD /*T2T*/);
  hipLaunchKernelGGL(k7a_fft, dim3(1024), dim3(256), 0, stream, RD /*T2T*/, RA /*TY*/);
  hipLaunchKernelGGL(k8_irfft, dim3(1024), dim3(256), 0, stream, RA /*TY*/, out);
}

// Round 17
// 207.472 us; speedup vs baseline: 1.0445x; 1.0445x over previous
//
#include <hip/hip_runtime.h>
#include <hip/hip_bf16.h>
#include <math.h>

#define BB 4
#define CC 64
#define HH 128
#define WW 128
#define DD 128
#define NN 64
#define HF 128
#define WF 65
#define LL 8320
#define TSEG 64
#define NSEG 130
#define PI2f 6.283185307179586f

__device__ __forceinline__ int brev7(int x) { return (int)(__brev((unsigned)x) >> 25); }

// ---------------- K0: weight transposes (WcatT[k][o] 128x256, WoT[d][e] 128x128) ----
__global__ void k0_transpose(const float* __restrict__ Wx, const float* __restrict__ Wb,
                             const float* __restrict__ Wc, const float* __restrict__ Wout,
                             float* __restrict__ WcatT, float* __restrict__ WoT) {
  int idx = blockIdx.x * 256 + threadIdx.x;
  if (idx < 128 * 256) {
    int k = idx >> 8, o = idx & 255;
    float v;
    if (o < 128)      v = Wx[o * 128 + k];
    else if (o < 192) v = Wb[(o - 128) * 128 + k];
    else              v = Wc[(o - 192) * 128 + k];
    WcatT[k * 256 + o] = v;
  }
  if (idx < 128 * 128) {
    int d = idx >> 7, e = idx & 127;
    WoT[d * 128 + e] = Wout[e * 128 + d];
  }
}

// ---------------- K1: rfft along W via paired 128-pt complex FFT (16 pairs/block) --
__global__ __launch_bounds__(256) void k1_rfft(const float* __restrict__ x,
                                               float* __restrict__ T1) {
  __shared__ float2 data[128 * 17];
  __shared__ float2 tw[64];
  int tid = threadIdx.x;
  if (tid < 64) {
    float sv, cv;
    sincosf(PI2f * (float)tid * (1.f / 128.f), &sv, &cv);
    tw[tid] = make_float2(cv, sv);
  }
  int r0 = blockIdx.x * 32;            // 32 rows = 16 pairs
  const float* xp = x + (size_t)r0 * 128;
#pragma unroll
  for (int i = 0; i < 8; i++) {
    int e = i * 256 + tid;             // 2048: p = e>>7, j = e&127
    int p = e >> 7, j = e & 127;
    float v1 = xp[(2 * p) * 128 + j];
    float v2 = xp[(2 * p + 1) * 128 + j];
    data[brev7(j) * 17 + p] = make_float2(v1, v2);
  }
  __syncthreads();
  for (int s = 1; s <= 7; s++) {
    int half = 1 << (s - 1);
    int tsh = 7 - s;
#pragma unroll
    for (int i = 0; i < 4; i++) {
      int idx = i * 256 + tid;         // 1024 butterflies: t = idx>>4, c = idx&15
      int t = idx >> 4, c = idx & 15;
      int j = t & (half - 1);
      int pos = ((t >> (s - 1)) << s) + j;
      float2 a = data[pos * 17 + c];
      float2 b = data[(pos + half) * 17 + c];
      float2 w = tw[j << tsh];
      float2 m = make_float2(b.x * w.x + b.y * w.y, b.y * w.x - b.x * w.y);  // e^{-i}
      data[pos * 17 + c] = make_float2(a.x + m.x, a.y + m.y);
      data[(pos + half) * 17 + c] = make_float2(a.x - m.x, a.y - m.y);
    }
    __syncthreads();
  }
  const float inv = 1.f / 128.f;
  float2* o = (float2*)T1 + (size_t)r0 * 65;
#pragma unroll
  for (int i = 0; i < 5; i++) {
    int e = i * 256 + tid;             // 16 pairs x 65 bins = 1040
    if (e < 1040) {
      int p = e / 65, k = e - p * 65;
      float2 Z = data[k * 17 + p];
      float2 Zc = data[((128 - k) & 127) * 17 + p];
      float2 X1 = make_float2((Z.x + Zc.x) * 0.5f * inv, (Z.y - Zc.y) * 0.5f * inv);
      float2 X2 = make_float2((Z.y + Zc.y) * 0.5f * inv, (Zc.x - Z.x) * 0.5f * inv);
      o[(2 * p) * 65 + k] = X1;
      o[(2 * p + 1) * 65 + k] = X2;
    }
  }
}

// ---------------- K2a: radix-2 FFT (forward) along H, 17 wf-cols per block ---------
__global__ __launch_bounds__(256) void k2a_fft(const float* __restrict__ T1,
                                               float* __restrict__ uT) {
  __shared__ float2 data[128 * 17];
  __shared__ float2 tw[64];
  int tid = threadIdx.x;
  if (tid < 64) {
    float sv, cv;
    sincosf(PI2f * (float)tid * (1.f / 128.f), &sv, &cv);
    tw[tid] = make_float2(cv, sv);
  }
  int chunk = blockIdx.x & 3;
  int bc = blockIdx.x >> 2;
  int wf0 = chunk * 16;
  const float2* Tp = (const float2*)T1 + (size_t)bc * 8320;  // [j][wf], 65-wide
#pragma unroll
  for (int i = 0; i < 9; i++) {
    int e = i * 256 + tid;  // e = j*17 + c
    if (e < 2176) {
      int j = e / 17;
      int c = e - j * 17;
      data[brev7(j) * 17 + c] = Tp[j * 65 + wf0 + c];
    }
  }
  __syncthreads();
  for (int s = 1; s <= 7; s++) {
    int half = 1 << (s - 1);
    int tsh = 7 - s;
#pragma unroll
    for (int i = 0; i < 5; i++) {
      int idx = i * 256 + tid;
      if (idx < 1088) {
        int t = idx / 17;
        int c = idx - t * 17;
        int j = t & (half - 1);
        int pos = ((t >> (s - 1)) << s) + j;
        float2 a = data[pos * 17 + c];
        float2 b = data[(pos + half) * 17 + c];
        float2 w = tw[j << tsh];
        float2 m = make_float2(b.x * w.x + b.y * w.y, b.y * w.x - b.x * w.y);  // b*e^{-i}
        data[pos * 17 + c] = make_float2(a.x + m.x, a.y + m.y);
        data[(pos + half) * 17 + c] = make_float2(a.x - m.x, a.y - m.y);
      }
    }
    __syncthreads();
  }
  int b = bc >> 6, ch = bc & 63;
  float* pr = uT + (size_t)(b * 128 + ch) * 8320;
  float* pi = uT + (size_t)(b * 128 + 64 + ch) * 8320;
#pragma unroll
  for (int i = 0; i < 9; i++) {
    int e = i * 256 + tid;
    if (e < 2176) {
      int hf = e / 17;
      int c = e - hf * 17;
      float2 v = data[hf * 17 + c];
      pr[hf * 65 + wf0 + c] = v.x;
      pi[hf * 65 + wf0 + c] = v.y;
    }
  }
}

// ---------------- K3: LN + projections; 32-token tile, 256 thr, grid 1040 ----------
__global__ __launch_bounds__(256) void k3_ln_proj(
    const float* __restrict__ uT, const float* __restrict__ WcatT,
    const float* __restrict__ nw, const float* __restrict__ nb,
    const float* __restrict__ wdt, const float* __restrict__ dtbias,
    float* __restrict__ xs, float* __restrict__ Bs, float* __restrict__ Cs,
    float* __restrict__ dtb) {
  __shared__ float su[128 * 36];       // [k][t], stride 36
  __shared__ float snw[128], snb[128], swdt[128];
  int tid = threadIdx.x;               // 0..255
  int b = blockIdx.x / 260, tile = blockIdx.x % 260;
  int l0 = tile * 32;
  if (tid < 128) { snw[tid] = nw[tid]; snb[tid] = nb[tid]; swdt[tid] = wdt[tid]; }
  const float* up = uT + (size_t)b * 128 * 8320 + l0;
#pragma unroll
  for (int i = 0; i < 4; i++) {
    int e = i * 256 + tid;             // 1024 f4: d = e>>3, q = e&7
    int d = e >> 3, q = e & 7;
    float4 v = *(const float4*)(up + (size_t)d * 8320 + q * 4);
    *(float4*)&su[d * 36 + q * 4] = v;
  }
  __syncthreads();
  // LayerNorm: 8 threads per token (j=0..7), 16 channels each, in-place in su
  int t = tid >> 3, j = tid & 7;       // t 0..31
  float vals[16];
  float s = 0.f, s2 = 0.f;
#pragma unroll
  for (int i = 0; i < 16; i++) {
    float v = su[(8 * i + j) * 36 + t];
    vals[i] = v; s += v; s2 += v * v;
  }
  s += __shfl_xor(s, 1, 64);  s += __shfl_xor(s, 2, 64);  s += __shfl_xor(s, 4, 64);
  s2 += __shfl_xor(s2, 1, 64); s2 += __shfl_xor(s2, 2, 64); s2 += __shfl_xor(s2, 4, 64);
  float mu = s * (1.f / 128.f);
  float var = s2 * (1.f / 128.f) - mu * mu;
  float rs = rsqrtf(var + 1e-5f);
  float raw = 0.f;
#pragma unroll
  for (int i = 0; i < 16; i++) {
    int k = 8 * i + j;
    float v = ((vals[i] - mu) * rs * snw[k] + snb[k]) * (1.f / 128.f);
    su[k * 36 + t] = v;
    raw = fmaf(v, swdt[k], raw);
  }
  raw += __shfl_xor(raw, 1, 64); raw += __shfl_xor(raw, 2, 64); raw += __shfl_xor(raw, 4, 64);
  if (j == 0) {
    float z = raw + dtbias[0];
    float sp = fmaxf(z, 0.f) + log1pf(expf(-fabsf(z)));
    dtb[b * LL + l0 + t] = sp;
  }
  __syncthreads();
  // GEMM: wave = 8-token group (4 waves), lane = f4 of 256 outputs
  int wv = tid >> 6;                   // 0..3
  int lane = tid & 63;
  int t0 = wv * 8;
  float acc[8][4];
#pragma unroll
  for (int i = 0; i < 8; i++)
#pragma unroll
    for (int r = 0; r < 4; r++) acc[i][r] = 0.f;
  const float4* W4 = (const float4*)WcatT;
  for (int k = 0; k < 128; k++) {
    float4 w = W4[k * 64 + lane];
    const float4* sr4 = (const float4*)&su[k * 36 + t0];
    float4 u0 = sr4[0], u1 = sr4[1];
    float uk[8] = {u0.x, u0.y, u0.z, u0.w, u1.x, u1.y, u1.z, u1.w};
#pragma unroll
    for (int i = 0; i < 8; i++) {
      acc[i][0] = fmaf(w.x, uk[i], acc[i][0]);
      acc[i][1] = fmaf(w.y, uk[i], acc[i][1]);
      acc[i][2] = fmaf(w.z, uk[i], acc[i][2]);
      acc[i][3] = fmaf(w.w, uk[i], acc[i][3]);
    }
  }
  size_t tok0 = (size_t)b * LL + l0 + t0;
  float* basep;
  size_t stride;
  if (lane < 32)      { basep = xs + tok0 * 128 + lane * 4;        stride = 128; }
  else if (lane < 48) { basep = Bs + tok0 * 64 + (lane - 32) * 4;  stride = 64; }
  else                { basep = Cs + tok0 * 64 + (lane - 48) * 4;  stride = 64; }
#pragma unroll
  for (int i = 0; i < 8; i++)
    *(float4*)(basep + (size_t)i * stride) =
        make_float4(acc[i][0], acc[i][1], acc[i][2], acc[i][3]);
}

// ---------------- K5: half-D split (grid 1040), sX staged, interleaved G mapping ---
__global__ __launch_bounds__(256) void k5_seg(
    const float* __restrict__ xs, const float* __restrict__ Bs, const float* __restrict__ Cs,
    const float* __restrict__ dtb, const float* __restrict__ Alog,
    const float* __restrict__ Dskip,
    float* __restrict__ ybuf, float* __restrict__ Sseg, float* __restrict__ ssegb,
    float* __restrict__ cumg) {
  __shared__ __align__(16) float sX[64 * 68];    // 64 tokens x 64 d (half) padded
  __shared__ __align__(16) float sB[64 * 68];
  __shared__ __align__(16) float sCM[64 * 68];
  __shared__ float sdt[64], slc[64], sws[64];
  int tid = threadIdx.x;
  int half = blockIdx.x & 1;
  int bs = blockIdx.x >> 1;
  int b = bs / NSEG, seg = bs % NSEG;
  int tokbase = b * LL + seg * TSEG;
  const float4* xg = (const float4*)(xs + (size_t)tokbase * 128);
#pragma unroll
  for (int i = 0; i < 4; i++) {
    int e = i * 256 + tid;             // 1024: t = e>>4, q = e&15
    int t = e >> 4, q = e & 15;
    *(float4*)&sX[t * 68 + q * 4] = xg[t * 32 + half * 16 + q];
  }
  const float4* bg = (const float4*)(Bs + (size_t)tokbase * 64);
  const float4* cg = (const float4*)(Cs + (size_t)tokbase * 64);
#pragma unroll
  for (int i = 0; i < 4; i++) {
    int e = i * 256 + tid;
    int t = e >> 4, n4 = e & 15;
    *(float4*)&sB[t * 68 + n4 * 4] = bg[e];
    *(float4*)&sCM[t * 68 + n4 * 4] = cg[e];
  }
  if (tid < 64) sdt[tid] = dtb[tokbase + tid];
  __syncthreads();
  if (tid < 64) {
    float a = expf(Alog[0]);
    float v = -a * sdt[tid];
#pragma unroll
    for (int off = 1; off < 64; off <<= 1) {
      float o = __shfl_up(v, off, 64);
      if (tid >= off) v += o;
    }
    slc[tid] = v;
    float l63 = __shfl(v, 63, 64);
    sws[tid] = expf(l63 - v) * sdt[tid];
    if (half == 0) {
      cumg[tokbase + tid] = expf(v);
      if (tid == 63) ssegb[seg * BB + b] = expf(v);
    }
  }
  __syncthreads();
  // ---- G = C . B^T : thread = 4t x {sl, sl+16, sl+32, sl+48} (interleaved s)
  int t0 = (tid >> 4) * 4, sl = tid & 15;
  float g[4][4];
#pragma unroll
  for (int i = 0; i < 4; i++)
#pragma unroll
    for (int j = 0; j < 4; j++) g[i][j] = 0.f;
  for (int n4 = 0; n4 < 16; n4++) {
    float4 cr[4], br[4];
#pragma unroll
    for (int i = 0; i < 4; i++) cr[i] = *(const float4*)&sCM[(t0 + i) * 68 + n4 * 4];
#pragma unroll
    for (int j = 0; j < 4; j++) br[j] = *(const float4*)&sB[(sl + 16 * j) * 68 + n4 * 4];
#pragma unroll
    for (int i = 0; i < 4; i++)
#pragma unroll
      for (int j = 0; j < 4; j++) {
        g[i][j] = fmaf(cr[i].x, br[j].x, g[i][j]);
        g[i][j] = fmaf(cr[i].y, br[j].y, g[i][j]);
        g[i][j] = fmaf(cr[i].z, br[j].z, g[i][j]);
        g[i][j] = fmaf(cr[i].w, br[j].w, g[i][j]);
      }
  }
  __syncthreads();
  // ---- M (masked, scaled) into sCM ; scalar writes at consecutive banks
#pragma unroll
  for (int i = 0; i < 4; i++) {
    int t = t0 + i;
    float lt = slc[t];
#pragma unroll
    for (int j = 0; j < 4; j++) {
      int s = sl + 16 * j;
      float m = (s <= t) ? expf(lt - slc[s]) * sdt[s] * g[i][j] : 0.f;
      sCM[t * 68 + s] = m;
    }
  }
  __syncthreads();
  // ---- Y(half) = M . X + Dskip*X : thread = 4 tokens x 4 d
  {
    int d0 = (tid & 15) * 4;
    float acc[4][4];
#pragma unroll
    for (int i = 0; i < 4; i++)
#pragma unroll
      for (int j = 0; j < 4; j++) acc[i][j] = 0.f;
    for (int s = 0; s < 64; s++) {
      float4 xv = *(const float4*)&sX[s * 68 + d0];
#pragma unroll
      for (int i = 0; i < 4; i++) {
        float m = sCM[(t0 + i) * 68 + s];
        acc[i][0] = fmaf(m, xv.x, acc[i][0]);
        acc[i][1] = fmaf(m, xv.y, acc[i][1]);
        acc[i][2] = fmaf(m, xv.z, acc[i][2]);
        acc[i][3] = fmaf(m, xv.w, acc[i][3]);
      }
    }
    float4 dk = *(const float4*)&Dskip[half * 64 + d0];
#pragma unroll
    for (int i = 0; i < 4; i++) {
      int t = t0 + i;
      float4 xv = *(const float4*)&sX[t * 68 + d0];
      float4 y;
      y.x = fmaf(dk.x, xv.x, acc[i][0]);
      y.y = fmaf(dk.y, xv.y, acc[i][1]);
      y.z = fmaf(dk.z, xv.z, acc[i][2]);
      y.w = fmaf(dk.w, xv.w, acc[i][3]);
      *(float4*)(ybuf + (size_t)(tokbase + t) * 128 + half * 64 + d0) = y;
    }
  }
  // ---- S(half)[d,n] = sum_s sws[s] * X[s,d] * B[s,n] : thread = 4 d x 4 n
  {
    int dd0 = (tid >> 4) * 4, n0 = (tid & 15) * 4;
    float sacc[4][4];
#pragma unroll
    for (int k = 0; k < 4; k++)
#pragma unroll
      for (int j = 0; j < 4; j++) sacc[k][j] = 0.f;
    for (int s = 0; s < 64; s++) {
      float w = sws[s];
      float4 b4 = *(const float4*)&sB[s * 68 + n0];
      b4.x *= w; b4.y *= w; b4.z *= w; b4.w *= w;
      float4 xv = *(const float4*)&sX[s * 68 + dd0];
      float xk[4] = {xv.x, xv.y, xv.z, xv.w};
#pragma unroll
      for (int k = 0; k < 4; k++) {
        sacc[k][0] = fmaf(xk[k], b4.x, sacc[k][0]);
        sacc[k][1] = fmaf(xk[k], b4.y, sacc[k][1]);
        sacc[k][2] = fmaf(xk[k], b4.z, sacc[k][2]);
        sacc[k][3] = fmaf(xk[k], b4.w, sacc[k][3]);
      }
    }
    float* Sp = Sseg + (size_t)seg * 32768 + (size_t)b * 8192;
#pragma unroll
    for (int k = 0; k < 4; k++)
      *(float4*)&Sp[(half * 64 + dd0 + k) * 64 + n0] =
          make_float4(sacc[k][0], sacc[k][1], sacc[k][2], sacc[k][3]);
  }
}

// ---------------- K5b: segment-boundary state recurrence + h_last ------------------
__global__ void k5b_states(const float* __restrict__ h_prev, const float* __restrict__ Sseg,
                           const float* __restrict__ ssegb, float* __restrict__ Hp,
                           float* __restrict__ h_last) {
  int gid = blockIdx.x * 256 + threadIdx.x;
  int b = gid >> 13;
  float h = h_prev[gid];
  for (int p = 0; p < NSEG; p++) {
    Hp[(size_t)p * 32768 + gid] = h;
    h = fmaf(ssegb[p * 4 + b], h, Sseg[(size_t)p * 32768 + gid]);
  }
  h_last[gid] = h;
}

// ---------------- K5c: inter-segment correction, 512 thr ---------------------------
__global__ __launch_bounds__(512) void k5c_correct(
    const float* __restrict__ Cs, const float* __restrict__ Hp,
    const float* __restrict__ cumg, float* __restrict__ ybuf) {
  __shared__ __align__(16) float Ct[64 * 64];
  __shared__ __align__(16) float Ht[64 * 132];
  __shared__ float cg[64];
  int tid = threadIdx.x;               // 0..511
  int b = blockIdx.x / NSEG, seg = blockIdx.x % NSEG;
  int tokbase = b * LL + seg * 64;
  const float* Csrc = Cs + (size_t)tokbase * 64;
#pragma unroll
  for (int i = 0; i < 8; i++) {
    int e = tid + i * 512;
    Ct[(e & 63) * 64 + (e >> 6)] = Csrc[e];
  }
  const float* Hsrc = Hp + (size_t)seg * 32768 + (size_t)b * 8192;
#pragma unroll
  for (int i = 0; i < 16; i++) {
    int e = tid + i * 512;
    Ht[(e & 63) * 132 + (e >> 6)] = Hsrc[e];
  }
  if (tid < 64) cg[tid] = cumg[tokbase + tid];
  __syncthreads();
  int og = tid & 15, tg = tid >> 4;    // tg 0..31
  int d0 = og * 8, t0 = tg * 2;
  float acc[2][8];
#pragma unroll
  for (int i = 0; i < 2; i++)
#pragma unroll
    for (int jj = 0; jj < 8; jj++) acc[i][jj] = 0.f;
  for (int n = 0; n < 64; n++) {
    float2 c2 = *(const float2*)&Ct[n * 64 + t0];
    float4 h0 = *(const float4*)&Ht[n * 132 + d0];
    float4 h1 = *(const float4*)&Ht[n * 132 + d0 + 4];
    float cv[2] = {c2.x, c2.y};
    float hv[8] = {h0.x, h0.y, h0.z, h0.w, h1.x, h1.y, h1.z, h1.w};
#pragma unroll
    for (int i = 0; i < 2; i++)
#pragma unroll
      for (int jj = 0; jj < 8; jj++) acc[i][jj] = fmaf(cv[i], hv[jj], acc[i][jj]);
  }
#pragma unroll
  for (int i = 0; i < 2; i++) {
    float sc = cg[t0 + i];
    float* yp = ybuf + (size_t)(tokbase + t0 + i) * 128 + d0;
    float4 y0 = *(float4*)yp;
    float4 y1 = *(float4*)(yp + 4);
    y0.x = fmaf(sc, acc[i][0], y0.x); y0.y = fmaf(sc, acc[i][1], y0.y);
    y0.z = fmaf(sc, acc[i][2], y0.z); y0.w = fmaf(sc, acc[i][3], y0.w);
    y1.x = fmaf(sc, acc[i][4], y1.x); y1.y = fmaf(sc, acc[i][5], y1.y);
    y1.z = fmaf(sc, acc[i][6], y1.z); y1.w = fmaf(sc, acc[i][7], y1.w);
    *(float4*)yp = y0; *(float4*)(yp + 4) = y1;
  }
}

// ---------------- K6: output projection; 32-token tile, 256 thr, grid 1040 ---------
__global__ __launch_bounds__(256) void k6_outproj(
    const float* __restrict__ ybuf, const float* __restrict__ WoT,
    float* __restrict__ T2) {
  __shared__ float sy[128 * 36];   // [k][t] stride 36
  int tid = threadIdx.x;           // 0..255
  int b = blockIdx.x / 260, tile = blockIdx.x % 260;
  int l0 = tile * 32;
  const float* yg = ybuf + ((size_t)b * LL + l0) * 128;
#pragma unroll
  for (int i = 0; i < 4; i++) {
    int e = i * 256 + tid;           // 1024 f4: t = e>>5, q = e&31
    int t = e >> 5, q = e & 31;
    float4 v = *(const float4*)(yg + t * 128 + q * 4);
    sy[(q * 4 + 0) * 36 + t] = v.x; sy[(q * 4 + 1) * 36 + t] = v.y;
    sy[(q * 4 + 2) * 36 + t] = v.z; sy[(q * 4 + 3) * 36 + t] = v.w;
  }
  __syncthreads();
  // wave = 8-token group (4 waves); lane: th = lane>>5 (4-token half), o4 = lane&31
  int wv = tid >> 6;               // 0..3
  int lane = tid & 63;
  int o4 = lane & 31, th = lane >> 5;
  int tt0 = wv * 8 + th * 4;
  float acc[4][4];
#pragma unroll
  for (int i = 0; i < 4; i++)
#pragma unroll
    for (int r = 0; r < 4; r++) acc[i][r] = 0.f;
  const float4* W4 = (const float4*)WoT;
  for (int k = 0; k < 128; k++) {
    float4 w = W4[k * 32 + o4];
    const float4* sr4 = (const float4*)&sy[k * 36 + tt0];
    float4 u0 = sr4[0];
    float yk[4] = {u0.x, u0.y, u0.z, u0.w};
#pragma unroll
    for (int i = 0; i < 4; i++) {
      acc[i][0] = fmaf(w.x, yk[i], acc[i][0]);
      acc[i][1] = fmaf(w.y, yk[i], acc[i][1]);
      acc[i][2] = fmaf(w.z, yk[i], acc[i][2]);
      acc[i][3] = fmaf(w.w, yk[i], acc[i][3]);
    }
  }
#pragma unroll
  for (int i = 0; i < 4; i++) {
    int l = l0 + tt0 + i;
    *(float4*)(T2 + ((size_t)b * LL + l) * 128 + o4 * 4) =
        make_float4(acc[i][0] * 128.f, acc[i][1] * 128.f,
                    acc[i][2] * 128.f, acc[i][3] * 128.f);
  }
}

// ---------------- K7t: transpose T2[b][l][e] -> T2T[b][c][l] float2 ----------------
__global__ __launch_bounds__(256) void k7t_transpose(const float* __restrict__ T2,
                                                     float* __restrict__ T2T) {
  __shared__ __align__(16) float tile[32][132];
  int tid = threadIdx.x;
  int b = blockIdx.x / 260, lt = blockIdx.x % 260;
  int l0 = lt * 32;
#pragma unroll
  for (int i = 0; i < 4; i++) {
    int e = i * 256 + tid;  // 1024: 32 l x 32 f4
    int l = e >> 5, f4 = e & 31;
    float4 v = *(const float4*)(T2 + ((size_t)(b * LL + l0 + l)) * 128 + f4 * 4);
    *(float4*)&tile[l][f4 * 4] = v;
  }
  __syncthreads();
  int l = tid & 31, c2 = tid >> 5;  // c2 0..7
  float2* out = (float2*)T2T;
#pragma unroll
  for (int k = 0; k < 8; k++) {
    int c = c2 * 8 + k;
    float2 z = make_float2(tile[l][c], tile[l][64 + c]);
    out[((size_t)(b * 64 + c)) * 8320 + l0 + l] = z;
  }
}

// ---------------- K7a: radix-2 FFT (inverse) along H, 17 wf-cols per block ---------
__global__ __launch_bounds__(256) void k7a_fft(const float* __restrict__ T2T,
                                               float* __restrict__ TY) {
  __shared__ float2 data[128 * 17];
  __shared__ float2 tw[64];
  int tid = threadIdx.x;
  if (tid < 64) {
    float sv, cv;
    sincosf(PI2f * (float)tid * (1.f / 128.f), &sv, &cv);
    tw[tid] = make_float2(cv, sv);
  }
  int chunk = blockIdx.x & 3;
  int bc = blockIdx.x >> 2;
  int wf0 = chunk * 16;
  const float2* Zp = (const float2*)T2T + (size_t)bc * 8320;  // [j][wf], 65-wide
#pragma unroll
  for (int i = 0; i < 9; i++) {
    int e = i * 256 + tid;  // e = j*17 + c
    if (e < 2176) {
      int j = e / 17;
      int c = e - j * 17;
      data[brev7(j) * 17 + c] = Zp[j * 65 + wf0 + c];
    }
  }
  __syncthreads();
  for (int s = 1; s <= 7; s++) {
    int half = 1 << (s - 1);
    int tsh = 7 - s;
#pragma unroll
    for (int i = 0; i < 5; i++) {
      int idx = i * 256 + tid;
      if (idx < 1088) {
        int t = idx / 17;
        int c = idx - t * 17;
        int j = t & (half - 1);
        int pos = ((t >> (s - 1)) << s) + j;
        float2 a = data[pos * 17 + c];
        float2 b = data[(pos + half) * 17 + c];
        float2 w = tw[j << tsh];
        float2 m = make_float2(b.x * w.x - b.y * w.y, b.y * w.x + b.x * w.y);  // b*e^{+i}
        data[pos * 17 + c] = make_float2(a.x + m.x, a.y + m.y);
        data[(pos + half) * 17 + c] = make_float2(a.x - m.x, a.y - m.y);
      }
    }
    __syncthreads();
  }
  float2* po = (float2*)TY + (size_t)bc * 8320;
#pragma unroll
  for (int i = 0; i < 9; i++) {
    int e = i * 256 + tid;
    if (e < 2176) {
      int h = e / 17;
      int c = e - h * 17;
      po[h * 65 + wf0 + c] = data[h * 17 + c];
    }
  }
}

// ---------------- K8: irfft along W via paired Hermitian inverse FFT ---------------
__global__ __launch_bounds__(256) void k8_irfft(const float* __restrict__ TY,
                                                float* __restrict__ out) {
  __shared__ float2 zsh[32 * 66];
  __shared__ float2 data[128 * 17];
  __shared__ float2 tw[64];
  int tid = threadIdx.x;
  if (tid < 64) {
    float sv, cv;
    sincosf(PI2f * (float)tid * (1.f / 128.f), &sv, &cv);
    tw[tid] = make_float2(cv, sv);
  }
  int r0 = blockIdx.x * 32;            // 32 rows = 16 pairs
  const float2* Zp = (const float2*)TY + (size_t)r0 * 65;
#pragma unroll
  for (int i = 0; i < 9; i++) {
    int e = i * 256 + tid;             // 32*65 = 2080
    if (e < 2080) {
      int r = e / 65, wf = e - r * 65;
      zsh[r * 66 + wf] = Zp[r * 65 + wf];
    }
  }
  __syncthreads();
#pragma unroll
  for (int i = 0; i < 8; i++) {
    int e = i * 256 + tid;             // 2048: p = e>>7, j = e&127
    int p = e >> 7, j = e & 127;
    int jj = (j <= 64) ? j : 128 - j;
    float2 a1 = zsh[(2 * p) * 66 + jj];
    float2 a2 = zsh[(2 * p + 1) * 66 + jj];
    if (jj == 0 || jj == 64) { a1.y = 0.f; a2.y = 0.f; }
    float2 V = (j <= 64) ? make_float2(a1.x - a2.y, a1.y + a2.x)
                         : make_float2(a1.x + a2.y, a2.x - a1.y);
    data[brev7(j) * 17 + p] = V;
  }
  __syncthreads();
  for (int s = 1; s <= 7; s++) {
    int half = 1 << (s - 1);
    int tsh = 7 - s;
#pragma unroll
    for (int i = 0; i < 4; i++) {
      int idx = i * 256 + tid;         // 1024
      int t = idx >> 4, c = idx & 15;
      int j = t & (half - 1);
      int pos = ((t >> (s - 1)) << s) + j;
      float2 a = data[pos * 17 + c];
      float2 b = data[(pos + half) * 17 + c];
      float2 w = tw[j << tsh];
      float2 m = make_float2(b.x * w.x - b.y * w.y, b.y * w.x + b.x * w.y);  // e^{+i}
      data[pos * 17 + c] = make_float2(a.x + m.x, a.y + m.y);
      data[(pos + half) * 17 + c] = make_float2(a.x - m.x, a.y - m.y);
    }
    __syncthreads();
  }
  const float inv = 1.f / 128.f;
  float* op = out + (size_t)r0 * 128;
#pragma unroll
  for (int i = 0; i < 8; i++) {
    int e = i * 256 + tid;             // 2048: p = e>>7, w = e&127
    int p = e >> 7, w = e & 127;
    float2 X = data[w * 17 + p];
    op[(2 * p) * 128 + w] = X.x * inv;
    op[(2 * p + 1) * 128 + w] = X.y * inv;
  }
}

extern "C" void kernel_launch(void* const* d_in, const int* in_sizes, int n_in,
                              void* d_out, int out_size, void* d_ws, size_t ws_size,
                              hipStream_t stream) {
  const float* x      = (const float*)d_in[0];
  const float* h_prev = (const float*)d_in[1];
  const float* nw     = (const float*)d_in[2];
  const float* nb     = (const float*)d_in[3];
  const float* Wx     = (const float*)d_in[4];
  const float* Wb     = (const float*)d_in[5];
  const float* Wc     = (const float*)d_in[6];
  const float* wdt    = (const float*)d_in[7];
  const float* dtbias = (const float*)d_in[8];
  const float* Alog   = (const float*)d_in[9];
  const float* Dskip  = (const float*)d_in[10];
  const float* Wout   = (const float*)d_in[11];
  float* out = (float*)d_out;

  float* ws = (float*)d_ws;
  const size_t SZ_BIG = 4259840;  // B*L*D
  const size_t SZ_BN  = 2129920;  // B*L*N
  float* RA = ws;                 // T1 -> xs -> Hp -> TY
  float* RB = RA + SZ_BIG;        // uT -> ybuf
  float* RC = RB + SZ_BIG;        // Sseg -> T2
  float* RD = RC + SZ_BIG;        // Bs -> T2T (spans RD+RE)
  float* RE = RD + SZ_BN;         // Cs
  float* dtb   = RE + SZ_BN;      // 33280
  float* cumg  = dtb + 33280;     // 33280
  float* ssegb = cumg + 33280;    // 520
  float* WcatT = ssegb + 520;     // 32768
  float* WoT   = WcatT + 32768;   // 16384

  hipLaunchKernelGGL(k0_transpose, dim3(128), dim3(256), 0, stream, Wx, Wb, Wc, Wout, WcatT, WoT);
  hipLaunchKernelGGL(k1_rfft, dim3(1024), dim3(256), 0, stream, x, RA /*T1*/);
  hipLaunchKernelGGL(k2a_fft, dim3(1024), dim3(256), 0, stream, RA /*T1*/, RB /*uT*/);
  hipLaunchKernelGGL(k3_ln_proj, dim3(1040), dim3(256), 0, stream,
                     RB /*uT*/, WcatT, nw, nb, wdt, dtbias, RA /*xs*/, RD /*Bs*/, RE /*Cs*/, dtb);
  hipLaunchKernelGGL(k5_seg, dim3(1040), dim3(256), 0, stream,
                     RA /*xs*/, RD /*Bs*/, RE /*Cs*/, dtb, Alog, Dskip,
                     RB /*ybuf*/, RC /*Sseg*/, ssegb, cumg);
  hipLaunchKernelGGL(k5b_states, dim3(128), dim3(256), 0, stream,
                     h_prev, RC /*Sseg*/, ssegb, RA /*Hp*/, out + 4194304);
  hipLaunchKernelGGL(k5c_correct, dim3(520), dim3(512), 0, stream,
                     RE /*Cs*/, RA /*Hp*/, cumg, RB /*ybuf*/);
  hipLaunchKernelGGL(k6_outproj, dim3(1040), dim3(256), 0, stream, RB /*ybuf*/, WoT, RC /*T2*/);
  hipLaunchKernelGGL(k7t_transpose, dim3(1040), dim3(256), 0, stream, RC /*T2*/, RD /*T2T*/);
  hipLaunchKernelGGL(k7a_fft, dim3(1024), dim3(256), 0, stream, RD /*T2T*/, RA /*TY*/);
  hipLaunchKernelGGL(k8_irfft, dim3(1024), dim3(256), 0, stream, RA /*TY*/, out);
}